// Round 1
// baseline (203.972 us; speedup 1.0000x reference)
//
#include <hip/hip_runtime.h>
#include <math.h>

#define B 8
#define S 2048
#define D 1024

// ---------------- block reduction helpers (blockDim.x == 256) ----------------
__device__ __forceinline__ float waveReduceSum(float v) {
#pragma unroll
    for (int k = 32; k >= 1; k >>= 1) v += __shfl_xor(v, k, 64);
    return v;
}
__device__ __forceinline__ float waveReduceMax(float v) {
#pragma unroll
    for (int k = 32; k >= 1; k >>= 1) v = fmaxf(v, __shfl_xor(v, k, 64));
    return v;
}
__device__ float blockReduceSum(float v) {
    __shared__ float sm[4];
    int lane = threadIdx.x & 63, wid = threadIdx.x >> 6;
    v = waveReduceSum(v);
    __syncthreads();
    if (lane == 0) sm[wid] = v;
    __syncthreads();
    return sm[0] + sm[1] + sm[2] + sm[3];
}
__device__ float blockReduceMax(float v) {
    __shared__ float sm[4];
    int lane = threadIdx.x & 63, wid = threadIdx.x >> 6;
    v = waveReduceMax(v);
    __syncthreads();
    if (lane == 0) sm[wid] = v;
    __syncthreads();
    return fmaxf(fmaxf(sm[0], sm[1]), fmaxf(sm[2], sm[3]));
}

// ---------------- [8,1024] vector-batch @ [1024,1024] weight -> atomicAdd acc ----------------
// grid (4, 8), block 256. blockIdx.x: 256-wide d' chunk; blockIdx.y: 128-wide d chunk.
// vin[b*vstride + d], W row-major [D,D]. Reads W exactly once across the grid.
__global__ void __launch_bounds__(256) k_vecmat8(const float* __restrict__ vin, long vstride,
                                                 const float* __restrict__ W,
                                                 const float* __restrict__ bias,
                                                 float* __restrict__ acc_out) {
    const int dp = blockIdx.x * 256 + threadIdx.x;
    const int d0 = blockIdx.y * 128;
    __shared__ float vs[8][128];
    for (int i = threadIdx.x; i < 8 * 128; i += 256) {
        int b = i >> 7, dd = i & 127;
        vs[b][dd] = vin[(size_t)b * vstride + d0 + dd];
    }
    __syncthreads();
    float acc[8] = {0.f, 0.f, 0.f, 0.f, 0.f, 0.f, 0.f, 0.f};
    for (int dd = 0; dd < 128; ++dd) {
        float wv = W[(size_t)(d0 + dd) * D + dp];
#pragma unroll
        for (int b = 0; b < 8; ++b) acc[b] += vs[b][dd] * wv;
    }
#pragma unroll
    for (int b = 0; b < 8; ++b) {
        float v = acc[b];
        if (bias && blockIdx.y == 0) v += bias[dp];
        atomicAdd(&acc_out[b * D + dp], v);
    }
}

// ---------------- u[b,d] = dot(Wk row d, q0[b]) ----------------
// grid 256, block 256: one wave per row d (1024 waves), 8 batches per wave.
__global__ void __launch_bounds__(256) k2_u(const float* __restrict__ Wk,
                                            const float* __restrict__ q0,
                                            float* __restrict__ u) {
    int wid = (blockIdx.x * 256 + threadIdx.x) >> 6;  // row d: 0..1023
    int lane = threadIdx.x & 63;
    const float4* Wk4 = (const float4*)(Wk + (size_t)wid * D);
    const float4* q04 = (const float4*)q0;
    float acc[8] = {0.f, 0.f, 0.f, 0.f, 0.f, 0.f, 0.f, 0.f};
#pragma unroll
    for (int i = 0; i < 4; ++i) {
        float4 wv = Wk4[lane + 64 * i];
#pragma unroll
        for (int b = 0; b < 8; ++b) {
            float4 qv = q04[b * 256 + lane + 64 * i];
            acc[b] += wv.x * qv.x + wv.y * qv.y + wv.z * qv.z + wv.w * qv.w;
        }
    }
#pragma unroll
    for (int b = 0; b < 8; ++b) {
        float v = waveReduceSum(acc[b]);
        if (lane == 0) u[b * D + wid] = v;
    }
}

// ---------------- scores[b,t] = x[b,t,:].u[b] / 32 ----------------
// grid 4096, block 256: one wave per (b,t).
__global__ void __launch_bounds__(256) k3_scores(const float* __restrict__ x,
                                                 const float* __restrict__ u,
                                                 float* __restrict__ scores) {
    int gw = (blockIdx.x * 256 + threadIdx.x) >> 6;  // 0..16383 = b*S+t
    int lane = threadIdx.x & 63;
    int b = gw >> 11;
    const float4* x4 = (const float4*)(x + (size_t)gw * D);
    const float4* u4 = (const float4*)(u + b * D);
    float acc = 0.f;
#pragma unroll
    for (int i = 0; i < 4; ++i) {
        float4 xv = x4[lane + 64 * i];
        float4 uv = u4[lane + 64 * i];
        acc += xv.x * uv.x + xv.y * uv.y + xv.z * uv.z + xv.w * uv.w;
    }
    acc = waveReduceSum(acc);
    if (lane == 0) scores[gw] = acc * 0.03125f;  // 1/sqrt(1024)
}

// ---------------- softmax over t (in-place), one block per batch ----------------
__global__ void __launch_bounds__(256) k4_softmax(float* __restrict__ scores) {
    float* s = scores + blockIdx.x * S;
    float v[8];
    float m = -INFINITY;
#pragma unroll
    for (int i = 0; i < 8; ++i) {
        v[i] = s[threadIdx.x + 256 * i];
        m = fmaxf(m, v[i]);
    }
    m = blockReduceMax(m);
    float sum = 0.f;
#pragma unroll
    for (int i = 0; i < 8; ++i) {
        v[i] = __expf(v[i] - m);
        sum += v[i];
    }
    sum = blockReduceSum(sum);
    float inv = 1.0f / sum;
#pragma unroll
    for (int i = 0; i < 8; ++i) s[threadIdx.x + 256 * i] = v[i] * inv;
}

// ---------------- w[b,:] += sum_t attn[b,t]*x[b,t,:] ----------------
// grid (64, 8), block 256: each block does 32 t's; thread owns 4 consecutive d (float4).
__global__ void __launch_bounds__(256) k5_wsum(const float* __restrict__ x,
                                               const float* __restrict__ attn,
                                               float* __restrict__ w) {
    int b = blockIdx.y;
    int t0 = blockIdx.x * 32;
    const float4* x4 = (const float4*)(x + (size_t)b * S * D);
    float4 acc = {0.f, 0.f, 0.f, 0.f};
    for (int t = t0; t < t0 + 32; ++t) {
        float a = attn[b * S + t];
        float4 xv = x4[(size_t)t * 256 + threadIdx.x];
        acc.x += a * xv.x;
        acc.y += a * xv.y;
        acc.z += a * xv.z;
        acc.w += a * xv.w;
    }
    float* wd = w + b * D + threadIdx.x * 4;
    atomicAdd(wd + 0, acc.x);
    atomicAdd(wd + 1, acc.y);
    atomicAdd(wd + 2, acc.z);
    atomicAdd(wd + 3, acc.w);
}

// ---------------- LN1: ln1 = LayerNorm(wacc + bv + x[b,0,:]; g1,b1) ----------------
__global__ void __launch_bounds__(256) k7_ln1(const float* __restrict__ wacc,
                                              const float* __restrict__ bv,
                                              const float* __restrict__ x,
                                              const float* __restrict__ g1,
                                              const float* __restrict__ b1,
                                              float* __restrict__ ln1) {
    int b = blockIdx.x;
    float vals[4];
    float s = 0.f, ss = 0.f;
#pragma unroll
    for (int i = 0; i < 4; ++i) {
        int dp = threadIdx.x * 4 + i;
        float t = wacc[b * D + dp] + bv[dp] + x[(size_t)b * S * D + dp];
        vals[i] = t;
        s += t;
        ss += t * t;
    }
    s = blockReduceSum(s);
    ss = blockReduceSum(ss);
    float mu = s * (1.0f / D);
    float var = ss * (1.0f / D) - mu * mu;
    float inv = rsqrtf(var + 1e-5f);
#pragma unroll
    for (int i = 0; i < 4; ++i) {
        int dp = threadIdx.x * 4 + i;
        ln1[b * D + dp] = (vals[i] - mu) * inv * g1[dp] + b1[dp];
    }
}

// ---------------- final: relu(hacc+bd)+ln1 -> LN2 -> @Wc + bc -> out[b,0..1] ----------------
__global__ void __launch_bounds__(256) k9_final(const float* __restrict__ hacc,
                                                const float* __restrict__ bd,
                                                const float* __restrict__ ln1,
                                                const float* __restrict__ g2,
                                                const float* __restrict__ b2,
                                                const float* __restrict__ Wc,
                                                const float* __restrict__ bc,
                                                float* __restrict__ out) {
    int b = blockIdx.x;
    float vals[4];
    float s = 0.f, ss = 0.f;
#pragma unroll
    for (int i = 0; i < 4; ++i) {
        int dp = threadIdx.x * 4 + i;
        float h = fmaxf(hacc[b * D + dp] + bd[dp], 0.f);
        float t = h + ln1[b * D + dp];
        vals[i] = t;
        s += t;
        ss += t * t;
    }
    s = blockReduceSum(s);
    ss = blockReduceSum(ss);
    float mu = s * (1.0f / D);
    float var = ss * (1.0f / D) - mu * mu;
    float inv = rsqrtf(var + 1e-5f);
    float p0 = 0.f, p1 = 0.f;
#pragma unroll
    for (int i = 0; i < 4; ++i) {
        int dp = threadIdx.x * 4 + i;
        float l2 = (vals[i] - mu) * inv * g2[dp] + b2[dp];
        p0 += l2 * Wc[dp * 2 + 0];
        p1 += l2 * Wc[dp * 2 + 1];
    }
    p0 = blockReduceSum(p0);
    p1 = blockReduceSum(p1);
    if (threadIdx.x == 0) {
        out[b * 2 + 0] = p0 + bc[0];
        out[b * 2 + 1] = p1 + bc[1];
    }
}

extern "C" void kernel_launch(void* const* d_in, const int* in_sizes, int n_in,
                              void* d_out, int out_size, void* d_ws, size_t ws_size,
                              hipStream_t stream) {
    const float* x  = (const float*)d_in[0];
    const float* Wq = (const float*)d_in[1];
    const float* bq = (const float*)d_in[2];
    const float* Wk = (const float*)d_in[3];
    // bk = d_in[4]: constant offset over t -> cancels in softmax (and is zero anyway)
    const float* Wv = (const float*)d_in[5];
    const float* bv = (const float*)d_in[6];
    const float* Wd = (const float*)d_in[7];
    const float* bd = (const float*)d_in[8];
    const float* g1 = (const float*)d_in[9];
    const float* b1 = (const float*)d_in[10];
    const float* g2 = (const float*)d_in[11];
    const float* b2 = (const float*)d_in[12];
    const float* Wc = (const float*)d_in[13];
    const float* bc = (const float*)d_in[14];
    float* out = (float*)d_out;

    float* ws     = (float*)d_ws;
    float* q0     = ws;          // [8,1024]  (zeroed, atomic acc)
    float* w_     = ws + 8192;   // [8,1024]  (zeroed, atomic acc)
    float* wacc   = ws + 16384;  // [8,1024]  (zeroed, atomic acc)
    float* hacc   = ws + 24576;  // [8,1024]  (zeroed, atomic acc)
    float* u      = ws + 32768;  // [8,1024]
    float* scores = ws + 40960;  // [8,2048]  (softmax in-place -> attn)
    float* ln1    = ws + 57344;  // [8,1024]

    // zero the four atomic accumulators (q0, w_, wacc, hacc)
    hipMemsetAsync(ws, 0, 32768 * sizeof(float), stream);

    // q0[b] = x[b,0,:] @ Wq + bq
    k_vecmat8<<<dim3(4, 8), 256, 0, stream>>>(x, (long)S * D, Wq, bq, q0);
    // u[b] = Wk @ q0[b]
    k2_u<<<256, 256, 0, stream>>>(Wk, q0, u);
    // scores[b,t] = x[b,t,:].u[b] / sqrt(D)
    k3_scores<<<4096, 256, 0, stream>>>(x, u, scores);
    // softmax over t
    k4_softmax<<<B, 256, 0, stream>>>(scores);
    // w[b] = sum_t attn[b,t] x[b,t,:]
    k5_wsum<<<dim3(64, 8), 256, 0, stream>>>(x, scores, w_);
    // weighted0(pre-bias) = w @ Wv
    k_vecmat8<<<dim3(4, 8), 256, 0, stream>>>(w_, 1024, Wv, nullptr, wacc);
    // ln1 = LN(wacc + bv + x[b,0,:])
    k7_ln1<<<B, 256, 0, stream>>>(wacc, bv, x, g1, b1, ln1);
    // hacc = ln1 @ Wd
    k_vecmat8<<<dim3(4, 8), 256, 0, stream>>>(ln1, 1024, Wd, nullptr, hacc);
    // out = LN2(relu(hacc+bd)+ln1) @ Wc + bc
    k9_final<<<B, 256, 0, stream>>>(hacc, bd, ln1, g2, b2, Wc, bc, out);
}

// Round 2
// 191.522 us; speedup vs baseline: 1.0650x; 1.0650x over previous
//
#include <hip/hip_runtime.h>
#include <math.h>

#define B 8
#define S 2048
#define D 1024

// ---------------- block reduction helpers (blockDim.x == 256) ----------------
__device__ __forceinline__ float waveReduceSum(float v) {
#pragma unroll
    for (int k = 32; k >= 1; k >>= 1) v += __shfl_xor(v, k, 64);
    return v;
}
__device__ __forceinline__ float waveReduceMax(float v) {
#pragma unroll
    for (int k = 32; k >= 1; k >>= 1) v = fmaxf(v, __shfl_xor(v, k, 64));
    return v;
}
__device__ float blockReduceSum(float v) {
    __shared__ float sm[4];
    int lane = threadIdx.x & 63, wid = threadIdx.x >> 6;
    v = waveReduceSum(v);
    __syncthreads();
    if (lane == 0) sm[wid] = v;
    __syncthreads();
    return sm[0] + sm[1] + sm[2] + sm[3];
}
__device__ float blockReduceMax(float v) {
    __shared__ float sm[4];
    int lane = threadIdx.x & 63, wid = threadIdx.x >> 6;
    v = waveReduceMax(v);
    __syncthreads();
    if (lane == 0) sm[wid] = v;
    __syncthreads();
    return fmaxf(fmaxf(sm[0], sm[1]), fmaxf(sm[2], sm[3]));
}

// ---------------- [8,1024] vector-batch @ [1024,1024] weight -> atomicAdd acc ----------------
// grid (4, 32), block 256. blockIdx.x: 256-wide d' chunk; blockIdx.y: 32-wide d chunk.
// 128 blocks total; W read exactly once across the grid.
__global__ void __launch_bounds__(256) k_vecmat8(const float* __restrict__ vin, long vstride,
                                                 const float* __restrict__ W,
                                                 const float* __restrict__ bias,
                                                 float* __restrict__ acc_out) {
    const int dp = blockIdx.x * 256 + threadIdx.x;
    const int d0 = blockIdx.y * 32;
    __shared__ float vs[8][32];
    if (threadIdx.x < 256) {
        int i = threadIdx.x;
        if (i < 8 * 32) {
            int b = i >> 5, dd = i & 31;
            vs[b][dd] = vin[(size_t)b * vstride + d0 + dd];
        }
    }
    __syncthreads();
    float acc[8] = {0.f, 0.f, 0.f, 0.f, 0.f, 0.f, 0.f, 0.f};
#pragma unroll 4
    for (int dd = 0; dd < 32; ++dd) {
        float wv = W[(size_t)(d0 + dd) * D + dp];
#pragma unroll
        for (int b = 0; b < 8; ++b) acc[b] += vs[b][dd] * wv;
    }
#pragma unroll
    for (int b = 0; b < 8; ++b) {
        float v = acc[b];
        if (bias && blockIdx.y == 0) v += bias[dp];
        atomicAdd(&acc_out[b * D + dp], v);
    }
}

// ---------------- u[b,d] = dot(Wk row d, q0[b]) ----------------
// grid 256, block 256: one wave per row d (1024 waves), 8 batches per wave.
__global__ void __launch_bounds__(256) k2_u(const float* __restrict__ Wk,
                                            const float* __restrict__ q0,
                                            float* __restrict__ u) {
    int wid = (blockIdx.x * 256 + threadIdx.x) >> 6;  // row d: 0..1023
    int lane = threadIdx.x & 63;
    const float4* Wk4 = (const float4*)(Wk + (size_t)wid * D);
    const float4* q04 = (const float4*)q0;
    float acc[8] = {0.f, 0.f, 0.f, 0.f, 0.f, 0.f, 0.f, 0.f};
#pragma unroll
    for (int i = 0; i < 4; ++i) {
        float4 wv = Wk4[lane + 64 * i];
#pragma unroll
        for (int b = 0; b < 8; ++b) {
            float4 qv = q04[b * 256 + lane + 64 * i];
            acc[b] += wv.x * qv.x + wv.y * qv.y + wv.z * qv.z + wv.w * qv.w;
        }
    }
#pragma unroll
    for (int b = 0; b < 8; ++b) {
        float v = waveReduceSum(acc[b]);
        if (lane == 0) u[b * D + wid] = v;
    }
}

// ---------------- scores[b,t] = x[b,t,:].u[b] / 32  (raw, unnormalized) ----------------
// grid 4096, block 256: one wave per (b,t).
__global__ void __launch_bounds__(256) k3_scores(const float* __restrict__ x,
                                                 const float* __restrict__ u,
                                                 float* __restrict__ scores) {
    int gw = (blockIdx.x * 256 + threadIdx.x) >> 6;  // 0..16383 = b*S+t
    int lane = threadIdx.x & 63;
    int b = gw >> 11;
    const float4* x4 = (const float4*)(x + (size_t)gw * D);
    const float4* u4 = (const float4*)(u + b * D);
    float acc = 0.f;
#pragma unroll
    for (int i = 0; i < 4; ++i) {
        float4 xv = x4[lane + 64 * i];
        float4 uv = u4[lane + 64 * i];
        acc += xv.x * uv.x + xv.y * uv.y + xv.z * uv.z + xv.w * uv.w;
    }
    acc = waveReduceSum(acc);
    if (lane == 0) scores[gw] = acc * 0.03125f;  // 1/sqrt(1024)
}

// ---------------- softmax stats per batch: stats[b] = {max, 1/sum(exp(s-max))} ----------------
__global__ void __launch_bounds__(256) k4_stats(const float* __restrict__ scores,
                                                float* __restrict__ stats) {
    const float* s = scores + blockIdx.x * S;
    float v[8];
    float m = -INFINITY;
#pragma unroll
    for (int i = 0; i < 8; ++i) {
        v[i] = s[threadIdx.x + 256 * i];
        m = fmaxf(m, v[i]);
    }
    m = blockReduceMax(m);
    float sum = 0.f;
#pragma unroll
    for (int i = 0; i < 8; ++i) sum += __expf(v[i] - m);
    sum = blockReduceSum(sum);
    if (threadIdx.x == 0) {
        stats[blockIdx.x * 2 + 0] = m;
        stats[blockIdx.x * 2 + 1] = 1.0f / sum;
    }
}

// ---------------- w[b,:] += sum_t softmax(scores)[b,t]*x[b,t,:] ----------------
// grid (128, 8), block 256: each block does 16 t's; thread owns 4 consecutive d (float4).
__global__ void __launch_bounds__(256) k5_wsum(const float* __restrict__ x,
                                               const float* __restrict__ scores,
                                               const float* __restrict__ stats,
                                               float* __restrict__ w) {
    int b = blockIdx.y;
    int t0 = blockIdx.x * 16;
    float m = stats[b * 2 + 0];
    float inv = stats[b * 2 + 1];
    const float4* x4 = (const float4*)(x + (size_t)b * S * D);
    float4 acc = {0.f, 0.f, 0.f, 0.f};
    for (int t = t0; t < t0 + 16; ++t) {
        float a = __expf(scores[b * S + t] - m) * inv;
        float4 xv = x4[(size_t)t * 256 + threadIdx.x];
        acc.x += a * xv.x;
        acc.y += a * xv.y;
        acc.z += a * xv.z;
        acc.w += a * xv.w;
    }
    float* wd = w + b * D + threadIdx.x * 4;
    atomicAdd(wd + 0, acc.x);
    atomicAdd(wd + 1, acc.y);
    atomicAdd(wd + 2, acc.z);
    atomicAdd(wd + 3, acc.w);
}

// ---------------- LN1: ln1 = LayerNorm(wacc + bv + x[b,0,:]; g1,b1) ----------------
__global__ void __launch_bounds__(256) k7_ln1(const float* __restrict__ wacc,
                                              const float* __restrict__ bv,
                                              const float* __restrict__ x,
                                              const float* __restrict__ g1,
                                              const float* __restrict__ b1,
                                              float* __restrict__ ln1) {
    int b = blockIdx.x;
    float vals[4];
    float s = 0.f, ss = 0.f;
#pragma unroll
    for (int i = 0; i < 4; ++i) {
        int dp = threadIdx.x * 4 + i;
        float t = wacc[b * D + dp] + bv[dp] + x[(size_t)b * S * D + dp];
        vals[i] = t;
        s += t;
        ss += t * t;
    }
    s = blockReduceSum(s);
    ss = blockReduceSum(ss);
    float mu = s * (1.0f / D);
    float var = ss * (1.0f / D) - mu * mu;
    float inv = rsqrtf(var + 1e-5f);
#pragma unroll
    for (int i = 0; i < 4; ++i) {
        int dp = threadIdx.x * 4 + i;
        ln1[b * D + dp] = (vals[i] - mu) * inv * g1[dp] + b1[dp];
    }
}

// ---------------- final: relu(hacc+bd)+ln1 -> LN2 -> @Wc + bc -> out[b,0..1] ----------------
__global__ void __launch_bounds__(256) k9_final(const float* __restrict__ hacc,
                                                const float* __restrict__ bd,
                                                const float* __restrict__ ln1,
                                                const float* __restrict__ g2,
                                                const float* __restrict__ b2,
                                                const float* __restrict__ Wc,
                                                const float* __restrict__ bc,
                                                float* __restrict__ out) {
    int b = blockIdx.x;
    float vals[4];
    float s = 0.f, ss = 0.f;
#pragma unroll
    for (int i = 0; i < 4; ++i) {
        int dp = threadIdx.x * 4 + i;
        float h = fmaxf(hacc[b * D + dp] + bd[dp], 0.f);
        float t = h + ln1[b * D + dp];
        vals[i] = t;
        s += t;
        ss += t * t;
    }
    s = blockReduceSum(s);
    ss = blockReduceSum(ss);
    float mu = s * (1.0f / D);
    float var = ss * (1.0f / D) - mu * mu;
    float inv = rsqrtf(var + 1e-5f);
    float p0 = 0.f, p1 = 0.f;
#pragma unroll
    for (int i = 0; i < 4; ++i) {
        int dp = threadIdx.x * 4 + i;
        float l2 = (vals[i] - mu) * inv * g2[dp] + b2[dp];
        p0 += l2 * Wc[dp * 2 + 0];
        p1 += l2 * Wc[dp * 2 + 1];
    }
    p0 = blockReduceSum(p0);
    p1 = blockReduceSum(p1);
    if (threadIdx.x == 0) {
        out[b * 2 + 0] = p0 + bc[0];
        out[b * 2 + 1] = p1 + bc[1];
    }
}

extern "C" void kernel_launch(void* const* d_in, const int* in_sizes, int n_in,
                              void* d_out, int out_size, void* d_ws, size_t ws_size,
                              hipStream_t stream) {
    const float* x  = (const float*)d_in[0];
    const float* Wq = (const float*)d_in[1];
    const float* bq = (const float*)d_in[2];
    const float* Wk = (const float*)d_in[3];
    // bk = d_in[4]: constant offset over t -> cancels in softmax
    const float* Wv = (const float*)d_in[5];
    const float* bv = (const float*)d_in[6];
    const float* Wd = (const float*)d_in[7];
    const float* bd = (const float*)d_in[8];
    const float* g1 = (const float*)d_in[9];
    const float* b1 = (const float*)d_in[10];
    const float* g2 = (const float*)d_in[11];
    const float* b2 = (const float*)d_in[12];
    const float* Wc = (const float*)d_in[13];
    const float* bc = (const float*)d_in[14];
    float* out = (float*)d_out;

    float* ws     = (float*)d_ws;
    float* q0     = ws;          // [8,1024]  (zeroed, atomic acc)
    float* w_     = ws + 8192;   // [8,1024]  (zeroed, atomic acc)
    float* wacc   = ws + 16384;  // [8,1024]  (zeroed, atomic acc)
    float* hacc   = ws + 24576;  // [8,1024]  (zeroed, atomic acc)
    float* u      = ws + 32768;  // [8,1024]
    float* scores = ws + 40960;  // [8,2048]  (raw scores)
    float* ln1    = ws + 57344;  // [8,1024]
    float* stats  = ws + 65536;  // [8,2] {max, 1/sum}

    // zero the four atomic accumulators (q0, w_, wacc, hacc)
    hipMemsetAsync(ws, 0, 32768 * sizeof(float), stream);

    // q0[b] = x[b,0,:] @ Wq + bq
    k_vecmat8<<<dim3(4, 32), 256, 0, stream>>>(x, (long)S * D, Wq, bq, q0);
    // u[b] = Wk @ q0[b]
    k2_u<<<256, 256, 0, stream>>>(Wk, q0, u);
    // scores[b,t] = x[b,t,:].u[b] / sqrt(D)
    k3_scores<<<4096, 256, 0, stream>>>(x, u, scores);
    // softmax stats per batch
    k4_stats<<<B, 256, 0, stream>>>(scores, stats);
    // w[b] = sum_t softmax[b,t] x[b,t,:]
    k5_wsum<<<dim3(128, 8), 256, 0, stream>>>(x, scores, stats, w_);
    // weighted0(pre-bias) = w @ Wv
    k_vecmat8<<<dim3(4, 32), 256, 0, stream>>>(w_, 1024, Wv, nullptr, wacc);
    // ln1 = LN(wacc + bv + x[b,0,:])
    k7_ln1<<<B, 256, 0, stream>>>(wacc, bv, x, g1, b1, ln1);
    // hacc = ln1 @ Wd
    k_vecmat8<<<dim3(4, 32), 256, 0, stream>>>(ln1, 1024, Wd, nullptr, hacc);
    // out = LN2(relu(hacc+bd)+ln1) @ Wc + bc
    k9_final<<<B, 256, 0, stream>>>(hacc, bd, ln1, g2, b2, Wc, bc, out);
}

// Round 3
// 185.254 us; speedup vs baseline: 1.1010x; 1.0338x over previous
//
#include <hip/hip_runtime.h>
#include <math.h>

#define B 8
#define S 2048
#define D 1024

// ---------------- reduction helpers ----------------
__device__ __forceinline__ float waveReduceSum(float v) {
#pragma unroll
    for (int k = 32; k >= 1; k >>= 1) v += __shfl_xor(v, k, 64);
    return v;
}
__device__ float blockReduceSum(float v) {
    __shared__ float sm[4];
    int lane = threadIdx.x & 63, wid = threadIdx.x >> 6;
    v = waveReduceSum(v);
    __syncthreads();
    if (lane == 0) sm[wid] = v;
    __syncthreads();
    return sm[0] + sm[1] + sm[2] + sm[3];
}

// ---------------- [8,1024] vector-batch @ [1024,1024] weight -> atomicAdd acc ----------------
// grid (4, 32), block 256. W read exactly once across the grid; split-K via atomics.
__global__ void __launch_bounds__(256) k_vecmat8(const float* __restrict__ vin, long vstride,
                                                 const float* __restrict__ W,
                                                 const float* __restrict__ bias,
                                                 float* __restrict__ acc_out) {
    const int dp = blockIdx.x * 256 + threadIdx.x;
    const int d0 = blockIdx.y * 32;
    __shared__ float vs[8][32];
    {
        int i = threadIdx.x;
        if (i < 8 * 32) {
            int b = i >> 5, dd = i & 31;
            vs[b][dd] = vin[(size_t)b * vstride + d0 + dd];
        }
    }
    __syncthreads();
    float acc[8] = {0.f, 0.f, 0.f, 0.f, 0.f, 0.f, 0.f, 0.f};
#pragma unroll 4
    for (int dd = 0; dd < 32; ++dd) {
        float wv = W[(size_t)(d0 + dd) * D + dp];
#pragma unroll
        for (int b = 0; b < 8; ++b) acc[b] += vs[b][dd] * wv;
    }
#pragma unroll
    for (int b = 0; b < 8; ++b) {
        float v = acc[b];
        if (bias && blockIdx.y == 0) v += bias[dp];
        atomicAdd(&acc_out[b * D + dp], v);
    }
}

// ---------------- u[b,d] = dot(Wk row d, q0[b]) ----------------
__global__ void __launch_bounds__(256) k2_u(const float* __restrict__ Wk,
                                            const float* __restrict__ q0,
                                            float* __restrict__ u) {
    int wid = (blockIdx.x * 256 + threadIdx.x) >> 6;
    int lane = threadIdx.x & 63;
    const float4* Wk4 = (const float4*)(Wk + (size_t)wid * D);
    const float4* q04 = (const float4*)q0;
    float acc[8] = {0.f, 0.f, 0.f, 0.f, 0.f, 0.f, 0.f, 0.f};
#pragma unroll
    for (int i = 0; i < 4; ++i) {
        float4 wv = Wk4[lane + 64 * i];
#pragma unroll
        for (int b = 0; b < 8; ++b) {
            float4 qv = q04[b * 256 + lane + 64 * i];
            acc[b] += wv.x * qv.x + wv.y * qv.y + wv.z * qv.z + wv.w * qv.w;
        }
    }
#pragma unroll
    for (int b = 0; b < 8; ++b) {
        float v = waveReduceSum(acc[b]);
        if (lane == 0) u[b * D + wid] = v;
    }
}

// ---------------- fused: scores + online-softmax partial weighted sums (single x pass) ----
// grid (128, 8), block 256. Block handles 16 t's of batch b:
//   s_t = x[b,t,:].u[b]/32 ; m = max s ; p_t = exp(s_t - m) ; l = sum p
//   w_loc[d] = sum_t p_t x[b,t,d]  (unnormalized)
// Writes per-block partial (m, l, w_loc[1024]).
__global__ void __launch_bounds__(256) k_attn_part(const float* __restrict__ x,
                                                   const float* __restrict__ u,
                                                   float* __restrict__ pml,
                                                   float* __restrict__ pw) {
    const int b = blockIdx.y;
    const int t0 = blockIdx.x * 16;
    const int wave = threadIdx.x >> 6, lane = threadIdx.x & 63;
    const float4* xb4 = (const float4*)(x + (size_t)b * S * D);
    const float4* u4 = (const float4*)(u + b * D);

    // phase A: 4 waves x 4 rows each -> 16 scores
    float acc[4] = {0.f, 0.f, 0.f, 0.f};
    const int tw = t0 + wave * 4;
#pragma unroll
    for (int i = 0; i < 4; ++i) {
        float4 uv = u4[lane + 64 * i];
#pragma unroll
        for (int r = 0; r < 4; ++r) {
            float4 xv = xb4[(size_t)(tw + r) * 256 + lane + 64 * i];
            acc[r] += xv.x * uv.x + xv.y * uv.y + xv.z * uv.z + xv.w * uv.w;
        }
    }
    __shared__ float s_sc[16];
#pragma unroll
    for (int r = 0; r < 4; ++r) {
        float v = waveReduceSum(acc[r]);
        if (lane == 0) s_sc[wave * 4 + r] = v * 0.03125f;  // /sqrt(1024)
    }
    __syncthreads();

    // phase B: local softmax (redundant per-thread, 16 values) + weighted partial
    float p[16];
    float m = -INFINITY;
#pragma unroll
    for (int i = 0; i < 16; ++i) m = fmaxf(m, s_sc[i]);
    float l = 0.f;
#pragma unroll
    for (int i = 0; i < 16; ++i) {
        p[i] = __expf(s_sc[i] - m);
        l += p[i];
    }
    float4 wl = {0.f, 0.f, 0.f, 0.f};
#pragma unroll 4
    for (int i = 0; i < 16; ++i) {
        float4 xv = xb4[(size_t)(t0 + i) * 256 + threadIdx.x];
        wl.x += p[i] * xv.x;
        wl.y += p[i] * xv.y;
        wl.z += p[i] * xv.z;
        wl.w += p[i] * xv.w;
    }
    const int pidx = b * 128 + blockIdx.x;
    ((float4*)(pw + (size_t)pidx * 1024))[threadIdx.x] = wl;
    if (threadIdx.x == 0) {
        pml[pidx * 2 + 0] = m;
        pml[pidx * 2 + 1] = l;
    }
}

// ---------------- combine partials: w[b,d] = sum_blk exp(m_blk - M) w_blk[d] / L --------
// grid (4, 8), block 256.
__global__ void __launch_bounds__(256) k_attn_comb(const float* __restrict__ pml,
                                                   const float* __restrict__ pw,
                                                   float* __restrict__ w) {
    const int b = blockIdx.y;
    const int d = blockIdx.x * 256 + threadIdx.x;
    __shared__ float s_scale[128];
    // global max (redundant per-thread; broadcast loads)
    float M = -INFINITY;
#pragma unroll 8
    for (int blk = 0; blk < 128; ++blk) M = fmaxf(M, pml[(b * 128 + blk) * 2]);
    float L = 0.f;
#pragma unroll 8
    for (int blk = 0; blk < 128; ++blk)
        L += __expf(pml[(b * 128 + blk) * 2] - M) * pml[(b * 128 + blk) * 2 + 1];
    if (threadIdx.x < 128)
        s_scale[threadIdx.x] = __expf(pml[(b * 128 + threadIdx.x) * 2] - M);
    __syncthreads();
    float acc = 0.f;
#pragma unroll 4
    for (int blk = 0; blk < 128; ++blk)
        acc += s_scale[blk] * pw[(size_t)(b * 128 + blk) * 1024 + d];
    w[b * D + d] = acc / L;
}

// ---------------- LN1: ln1 = LayerNorm(wacc + bv + x[b,0,:]; g1,b1) ----------------
__global__ void __launch_bounds__(256) k7_ln1(const float* __restrict__ wacc,
                                              const float* __restrict__ bv,
                                              const float* __restrict__ x,
                                              const float* __restrict__ g1,
                                              const float* __restrict__ b1,
                                              float* __restrict__ ln1) {
    int b = blockIdx.x;
    float vals[4];
    float s = 0.f, ss = 0.f;
#pragma unroll
    for (int i = 0; i < 4; ++i) {
        int dp = threadIdx.x * 4 + i;
        float t = wacc[b * D + dp] + bv[dp] + x[(size_t)b * S * D + dp];
        vals[i] = t;
        s += t;
        ss += t * t;
    }
    s = blockReduceSum(s);
    ss = blockReduceSum(ss);
    float mu = s * (1.0f / D);
    float var = ss * (1.0f / D) - mu * mu;
    float inv = rsqrtf(var + 1e-5f);
#pragma unroll
    for (int i = 0; i < 4; ++i) {
        int dp = threadIdx.x * 4 + i;
        ln1[b * D + dp] = (vals[i] - mu) * inv * g1[dp] + b1[dp];
    }
}

// ---------------- final: relu(hacc+bd)+ln1 -> LN2 -> @Wc + bc -> out ----------------
__global__ void __launch_bounds__(256) k9_final(const float* __restrict__ hacc,
                                                const float* __restrict__ bd,
                                                const float* __restrict__ ln1,
                                                const float* __restrict__ g2,
                                                const float* __restrict__ b2,
                                                const float* __restrict__ Wc,
                                                const float* __restrict__ bc,
                                                float* __restrict__ out) {
    int b = blockIdx.x;
    float vals[4];
    float s = 0.f, ss = 0.f;
#pragma unroll
    for (int i = 0; i < 4; ++i) {
        int dp = threadIdx.x * 4 + i;
        float h = fmaxf(hacc[b * D + dp] + bd[dp], 0.f);
        float t = h + ln1[b * D + dp];
        vals[i] = t;
        s += t;
        ss += t * t;
    }
    s = blockReduceSum(s);
    ss = blockReduceSum(ss);
    float mu = s * (1.0f / D);
    float var = ss * (1.0f / D) - mu * mu;
    float inv = rsqrtf(var + 1e-5f);
    float p0 = 0.f, p1 = 0.f;
#pragma unroll
    for (int i = 0; i < 4; ++i) {
        int dp = threadIdx.x * 4 + i;
        float l2 = (vals[i] - mu) * inv * g2[dp] + b2[dp];
        p0 += l2 * Wc[dp * 2 + 0];
        p1 += l2 * Wc[dp * 2 + 1];
    }
    p0 = blockReduceSum(p0);
    p1 = blockReduceSum(p1);
    if (threadIdx.x == 0) {
        out[b * 2 + 0] = p0 + bc[0];
        out[b * 2 + 1] = p1 + bc[1];
    }
}

extern "C" void kernel_launch(void* const* d_in, const int* in_sizes, int n_in,
                              void* d_out, int out_size, void* d_ws, size_t ws_size,
                              hipStream_t stream) {
    const float* x  = (const float*)d_in[0];
    const float* Wq = (const float*)d_in[1];
    const float* bq = (const float*)d_in[2];
    const float* Wk = (const float*)d_in[3];
    // bk (d_in[4]): constant over t -> cancels in softmax
    const float* Wv = (const float*)d_in[5];
    const float* bv = (const float*)d_in[6];
    const float* Wd = (const float*)d_in[7];
    const float* bd = (const float*)d_in[8];
    const float* g1 = (const float*)d_in[9];
    const float* b1 = (const float*)d_in[10];
    const float* g2 = (const float*)d_in[11];
    const float* b2 = (const float*)d_in[12];
    const float* Wc = (const float*)d_in[13];
    const float* bc = (const float*)d_in[14];
    float* out = (float*)d_out;

    float* ws   = (float*)d_ws;
    float* q0   = ws;           // [8,1024] atomic acc (zeroed)
    float* wacc = ws + 8192;    // [8,1024] atomic acc (zeroed)
    float* hacc = ws + 16384;   // [8,1024] atomic acc (zeroed)
    float* u    = ws + 24576;   // [8,1024]
    float* w_   = ws + 32768;   // [8,1024] (written whole by combine)
    float* ln1  = ws + 40960;   // [8,1024]
    float* pml  = ws + 49152;   // [8,128,2] partial (m, l)
    float* pw   = ws + 51200;   // [8,128,1024] partial weighted sums (4 MB, 16B-aligned)

    // zero the three atomic accumulators (contiguous)
    hipMemsetAsync(ws, 0, 24576 * sizeof(float), stream);

    // q0[b] = x[b,0,:] @ Wq + bq
    k_vecmat8<<<dim3(4, 32), 256, 0, stream>>>(x, (long)S * D, Wq, bq, q0);
    // u[b] = Wk @ q0[b]
    k2_u<<<256, 256, 0, stream>>>(Wk, q0, u);
    // fused scores + partial weighted sums (single pass over x)
    k_attn_part<<<dim3(128, 8), 256, 0, stream>>>(x, u, pml, pw);
    // combine partials -> w[b,:]
    k_attn_comb<<<dim3(4, 8), 256, 0, stream>>>(pml, pw, w_);
    // weighted0(pre-bias) = w @ Wv
    k_vecmat8<<<dim3(4, 32), 256, 0, stream>>>(w_, 1024, Wv, nullptr, wacc);
    // ln1 = LN(wacc + bv + x[b,0,:])
    k7_ln1<<<B, 256, 0, stream>>>(wacc, bv, x, g1, b1, ln1);
    // hacc = ln1 @ Wd
    k_vecmat8<<<dim3(4, 32), 256, 0, stream>>>(ln1, 1024, Wd, nullptr, hacc);
    // out = LN2(relu(hacc+bd)+ln1) @ Wc + bc
    k9_final<<<B, 256, 0, stream>>>(hacc, bd, ln1, g2, b2, Wc, bc, out);
}

// Round 5
// 172.190 us; speedup vs baseline: 1.1846x; 1.0759x over previous
//
#include <hip/hip_runtime.h>
#include <math.h>

#define B 8
#define S 2048
#define D 1024

// ---------------- reduction helpers (256-thread blocks) ----------------
__device__ __forceinline__ float waveReduceSum(float v) {
#pragma unroll
    for (int k = 32; k >= 1; k >>= 1) v += __shfl_xor(v, k, 64);
    return v;
}
__device__ __forceinline__ float waveReduceMax(float v) {
#pragma unroll
    for (int k = 32; k >= 1; k >>= 1) v = fmaxf(v, __shfl_xor(v, k, 64));
    return v;
}
__device__ float blockReduceSum(float v) {
    __shared__ float sm[4];
    int lane = threadIdx.x & 63, wid = threadIdx.x >> 6;
    v = waveReduceSum(v);
    __syncthreads();
    if (lane == 0) sm[wid] = v;
    __syncthreads();
    return sm[0] + sm[1] + sm[2] + sm[3];
}

// ---------------- K1: q0 = x0 @ Wq + bq (non-atomic, full-K per block) -------
// grid 64, block 256. Block owns a 16-wide dp chunk; 16 K-groups of 64.
// Also zeroes the wacc+hacc accumulator region (16384 floats, 256/block).
__global__ void __launch_bounds__(256) k1_q0(const float* __restrict__ x,
                                             const float* __restrict__ Wq,
                                             const float* __restrict__ bq,
                                             float* __restrict__ q0,
                                             float* __restrict__ zero_region) {
    const int tid = threadIdx.x;
    zero_region[blockIdx.x * 256 + tid] = 0.f;  // 64*256 == 16384 exactly

    const int dp0 = blockIdx.x * 16;
    const int dpl = tid & 15, kg = tid >> 4;
    __shared__ float xs[8][1024];
    for (int j = tid; j < 2048; j += 256) {  // 2048 float4 = 8 rows x 256
        int b = j >> 8, off = j & 255;
        ((float4*)xs[b])[off] = ((const float4*)(x + (size_t)b * S * D))[off];
    }
    __syncthreads();
    float acc[8] = {0.f, 0.f, 0.f, 0.f, 0.f, 0.f, 0.f, 0.f};
    const int k0 = kg * 64;
    for (int i = 0; i < 64; ++i) {
        int k = k0 + i;
        float wv = Wq[(size_t)k * D + dp0 + dpl];
#pragma unroll
        for (int b = 0; b < 8; ++b) acc[b] += xs[b][k] * wv;
    }
    __shared__ float red[16 * 16 * 9];  // (kg*16+dpl)*9 + b, pad stride 9
#pragma unroll
    for (int b = 0; b < 8; ++b) red[(kg * 16 + dpl) * 9 + b] = acc[b];
    __syncthreads();
    if (tid < 128) {
        int dpl2 = tid >> 3, b = tid & 7;
        float s = 0.f;
#pragma unroll
        for (int g = 0; g < 16; ++g) s += red[(g * 16 + dpl2) * 9 + b];
        q0[b * D + dp0 + dpl2] = s + bq[dp0 + dpl2];
    }
}

// ---------------- K2: u[b,row] = Wk[row,:] . q0[b,:] (one wave per row) ------
__global__ void __launch_bounds__(256) k2_u(const float* __restrict__ Wk,
                                            const float* __restrict__ q0,
                                            float* __restrict__ u) {
    int wid = (blockIdx.x * 256 + threadIdx.x) >> 6;  // row 0..1023
    int lane = threadIdx.x & 63;
    const float4* Wk4 = (const float4*)(Wk + (size_t)wid * D);
    const float4* q04 = (const float4*)q0;
    float acc[8] = {0.f, 0.f, 0.f, 0.f, 0.f, 0.f, 0.f, 0.f};
#pragma unroll
    for (int i = 0; i < 4; ++i) {
        float4 wv = Wk4[lane + 64 * i];
#pragma unroll
        for (int b = 0; b < 8; ++b) {
            float4 qv = q04[b * 256 + lane + 64 * i];
            acc[b] += wv.x * qv.x + wv.y * qv.y + wv.z * qv.z + wv.w * qv.w;
        }
    }
#pragma unroll
    for (int b = 0; b < 8; ++b) {
        float v = waveReduceSum(acc[b]);
        if (lane == 0) u[b * D + wid] = v;
    }
}

// ---------------- K3: fused scores + online-softmax partials (x once, in regs)
// grid (128, 8), block 256. Block: 16 t's of batch b.
__global__ void __launch_bounds__(256) k3_attn(const float* __restrict__ x,
                                               const float* __restrict__ u,
                                               float* __restrict__ pml,
                                               float* __restrict__ pw) {
    const int b = blockIdx.y;
    const int t0 = blockIdx.x * 16;
    const int tid = threadIdx.x;
    const int wave = tid >> 6, lane = tid & 63;
    const float4* xb4 = (const float4*)(x + (size_t)b * S * D);
    float4 xr[16];
#pragma unroll
    for (int t = 0; t < 16; ++t) xr[t] = xb4[(size_t)(t0 + t) * 256 + tid];
    float4 uv = ((const float4*)(u + b * D))[tid];
    __shared__ float part[16][256];
#pragma unroll
    for (int t = 0; t < 16; ++t)
        part[t][tid] = xr[t].x * uv.x + xr[t].y * uv.y + xr[t].z * uv.z + xr[t].w * uv.w;
    __syncthreads();
    __shared__ float s_sc[16];
#pragma unroll
    for (int r = 0; r < 4; ++r) {
        int t = wave * 4 + r;
        float v = part[t][lane] + part[t][lane + 64] + part[t][lane + 128] + part[t][lane + 192];
        v = waveReduceSum(v);
        if (lane == 0) s_sc[t] = v * 0.03125f;  // 1/sqrt(1024)
    }
    __syncthreads();
    float m = -INFINITY;
#pragma unroll
    for (int t = 0; t < 16; ++t) m = fmaxf(m, s_sc[t]);
    float p[16], l = 0.f;
#pragma unroll
    for (int t = 0; t < 16; ++t) {
        p[t] = __expf(s_sc[t] - m);
        l += p[t];
    }
    float4 wl = {0.f, 0.f, 0.f, 0.f};
#pragma unroll
    for (int t = 0; t < 16; ++t) {
        wl.x += p[t] * xr[t].x;
        wl.y += p[t] * xr[t].y;
        wl.z += p[t] * xr[t].z;
        wl.w += p[t] * xr[t].w;
    }
    const int pidx = b * 128 + blockIdx.x;
    ((float4*)(pw + (size_t)pidx * 1024))[tid] = wl;
    if (tid == 0) {
        pml[pidx * 2 + 0] = m;
        pml[pidx * 2 + 1] = l;
    }
}

// ---------------- K4: combine partials (local slice) + vecmat Wv -> wacc -----
// grid 128, block 256. K-chunk d0=(bid>>2)*32, dp-chunk (bid&3)*256.
__global__ void __launch_bounds__(256) k4_comb_wv(const float* __restrict__ pml,
                                                  const float* __restrict__ pw,
                                                  const float* __restrict__ Wv,
                                                  float* __restrict__ wacc) {
    const int tid = threadIdx.x;
    const int bid = blockIdx.x;
    const int d0 = (bid >> 2) * 32;
    const int dp = (bid & 3) * 256 + tid;
    const int wave = tid >> 6, lane = tid & 63;
    __shared__ float pm[8][128], pl[8][128], sc[8][128];
    __shared__ float sM[8], sL[8];
    __shared__ float vs[8][32];
    for (int j = tid; j < 1024; j += 256) {
        int b = j >> 7, blk = j & 127;
        pm[b][blk] = pml[(b * 128 + blk) * 2 + 0];
        pl[b][blk] = pml[(b * 128 + blk) * 2 + 1];
    }
    __syncthreads();
    // per-batch M and L: wave w handles batches w and w+4
#pragma unroll
    for (int h = 0; h < 2; ++h) {
        int b = wave + h * 4;
        float mv = fmaxf(pm[b][lane], pm[b][lane + 64]);
        float M = waveReduceMax(mv);
        float lp = __expf(pm[b][lane] - M) * pl[b][lane] +
                   __expf(pm[b][lane + 64] - M) * pl[b][lane + 64];
        float L = waveReduceSum(lp);
        if (lane == 0) {
            sM[b] = M;
            sL[b] = L;
        }
    }
    __syncthreads();
    for (int j = tid; j < 1024; j += 256) {
        int b = j >> 7, blk = j & 127;
        sc[b][blk] = __expf(pm[b][blk] - sM[b]);
    }
    __syncthreads();
    // combine: thread -> (b = tid>>5, dd = tid&31)
    {
        int b = tid >> 5, dd = tid & 31, d = d0 + dd;
        float acc = 0.f;
#pragma unroll 4
        for (int blk = 0; blk < 128; ++blk)
            acc += sc[b][blk] * pw[(size_t)(b * 128 + blk) * 1024 + d];
        vs[b][dd] = acc / sL[b];
    }
    __syncthreads();
    float acc[8] = {0.f, 0.f, 0.f, 0.f, 0.f, 0.f, 0.f, 0.f};
#pragma unroll 4
    for (int dd = 0; dd < 32; ++dd) {
        float wv = Wv[(size_t)(d0 + dd) * D + dp];
#pragma unroll
        for (int b = 0; b < 8; ++b) acc[b] += vs[b][dd] * wv;
    }
#pragma unroll
    for (int b = 0; b < 8; ++b) atomicAdd(&wacc[b * D + dp], acc[b]);
}

// ---------------- K5: redundant LN1 slice + vecmat Wd -> hacc ----------------
// grid 128, block 256.
__global__ void __launch_bounds__(256) k5_ln1_wd(const float* __restrict__ wacc,
                                                 const float* __restrict__ bv,
                                                 const float* __restrict__ x,
                                                 const float* __restrict__ g1,
                                                 const float* __restrict__ b1,
                                                 const float* __restrict__ Wd,
                                                 float* __restrict__ hacc) {
    const int tid = threadIdx.x;
    const int bid = blockIdx.x;
    const int d0 = (bid >> 2) * 32;
    const int dp = (bid & 3) * 256 + tid;
    __shared__ float sMu[8], sInv[8], vs[8][32];
    for (int b = 0; b < 8; ++b) {
        float s = 0.f, ss = 0.f;
#pragma unroll
        for (int i = 0; i < 4; ++i) {
            int e = tid * 4 + i;
            float v = wacc[b * D + e] + bv[e] + x[(size_t)b * S * D + e];
            s += v;
            ss += v * v;
        }
        s = blockReduceSum(s);
        ss = blockReduceSum(ss);
        if (tid == 0) {
            float mu = s * (1.0f / D);
            sMu[b] = mu;
            sInv[b] = rsqrtf(ss * (1.0f / D) - mu * mu + 1e-5f);
        }
    }
    __syncthreads();
    {
        int b = tid >> 5, dd = tid & 31, d = d0 + dd;
        float v = wacc[b * D + d] + bv[d] + x[(size_t)b * S * D + d];
        vs[b][dd] = (v - sMu[b]) * sInv[b] * g1[d] + b1[d];
    }
    __syncthreads();
    float acc[8] = {0.f, 0.f, 0.f, 0.f, 0.f, 0.f, 0.f, 0.f};
#pragma unroll 4
    for (int dd = 0; dd < 32; ++dd) {
        float wv = Wd[(size_t)(d0 + dd) * D + dp];
#pragma unroll
        for (int b = 0; b < 8; ++b) acc[b] += vs[b][dd] * wv;
    }
#pragma unroll
    for (int b = 0; b < 8; ++b) atomicAdd(&hacc[b * D + dp], acc[b]);
}

// ---------------- K6: recompute ln1 row + ReLU + LN2 + classifier -> out -----
// grid 8, block 256.
__global__ void __launch_bounds__(256) k6_final(const float* __restrict__ wacc,
                                                const float* __restrict__ bv,
                                                const float* __restrict__ x,
                                                const float* __restrict__ g1,
                                                const float* __restrict__ b1,
                                                const float* __restrict__ hacc,
                                                const float* __restrict__ bd,
                                                const float* __restrict__ g2,
                                                const float* __restrict__ b2,
                                                const float* __restrict__ Wc,
                                                const float* __restrict__ bc,
                                                float* __restrict__ out) {
    const int b = blockIdx.x;
    const int tid = threadIdx.x;
    float r[4];
    float s = 0.f, ss = 0.f;
#pragma unroll
    for (int i = 0; i < 4; ++i) {
        int e = tid * 4 + i;
        float v = wacc[b * D + e] + bv[e] + x[(size_t)b * S * D + e];
        r[i] = v;
        s += v;
        ss += v * v;
    }
    s = blockReduceSum(s);
    ss = blockReduceSum(ss);
    float mu1 = s * (1.0f / D);
    float inv1 = rsqrtf(ss * (1.0f / D) - mu1 * mu1 + 1e-5f);
    float t[4];
    float s2 = 0.f, ss2 = 0.f;
#pragma unroll
    for (int i = 0; i < 4; ++i) {
        int e = tid * 4 + i;
        float ln1v = (r[i] - mu1) * inv1 * g1[e] + b1[e];
        float h = fmaxf(hacc[b * D + e] + bd[e], 0.f) + ln1v;
        t[i] = h;
        s2 += h;
        ss2 += h * h;
    }
    s2 = blockReduceSum(s2);
    ss2 = blockReduceSum(ss2);
    float mu2 = s2 * (1.0f / D);
    float inv2 = rsqrtf(ss2 * (1.0f / D) - mu2 * mu2 + 1e-5f);
    float p0 = 0.f, p1 = 0.f;
#pragma unroll
    for (int i = 0; i < 4; ++i) {
        int e = tid * 4 + i;
        float l2 = (t[i] - mu2) * inv2 * g2[e] + b2[e];
        p0 += l2 * Wc[e * 2 + 0];
        p1 += l2 * Wc[e * 2 + 1];
    }
    p0 = blockReduceSum(p0);
    p1 = blockReduceSum(p1);
    if (tid == 0) {
        out[b * 2 + 0] = p0 + bc[0];
        out[b * 2 + 1] = p1 + bc[1];
    }
}

extern "C" void kernel_launch(void* const* d_in, const int* in_sizes, int n_in,
                              void* d_out, int out_size, void* d_ws, size_t ws_size,
                              hipStream_t stream) {
    const float* x  = (const float*)d_in[0];
    const float* Wq = (const float*)d_in[1];
    const float* bq = (const float*)d_in[2];
    const float* Wk = (const float*)d_in[3];
    // bk (d_in[4]): constant over t -> cancels in softmax
    const float* Wv = (const float*)d_in[5];
    const float* bv = (const float*)d_in[6];
    const float* Wd = (const float*)d_in[7];
    const float* bd = (const float*)d_in[8];
    const float* g1 = (const float*)d_in[9];
    const float* b1 = (const float*)d_in[10];
    const float* g2 = (const float*)d_in[11];
    const float* b2 = (const float*)d_in[12];
    const float* Wc = (const float*)d_in[13];
    const float* bc = (const float*)d_in[14];
    float* out = (float*)d_out;

    float* ws   = (float*)d_ws;
    float* q0   = ws;           // [8,1024] written whole by K1
    float* u    = ws + 8192;    // [8,1024]
    float* wacc = ws + 16384;   // [8,1024] zeroed by K1, atomics in K4
    float* hacc = ws + 24576;   // [8,1024] zeroed by K1, atomics in K5
    float* pml  = ws + 32768;   // [8,128,2]
    float* pw   = ws + 34816;   // [8,128,1024] (byte off 139264, 16B-aligned)

    // K1: q0 = x0 @ Wq + bq ; also zeroes wacc+hacc (contiguous 16384 floats)
    k1_q0<<<64, 256, 0, stream>>>(x, Wq, bq, q0, wacc);
    // K2: u = Wk @ q0
    k2_u<<<256, 256, 0, stream>>>(Wk, q0, u);
    // K3: attention partials (single x pass)
    k3_attn<<<dim3(128, 8), 256, 0, stream>>>(x, u, pml, pw);
    // K4: combine + @Wv -> wacc
    k4_comb_wv<<<128, 256, 0, stream>>>(pml, pw, Wv, wacc);
    // K5: LN1 (redundant) + @Wd -> hacc
    k5_ln1_wd<<<128, 256, 0, stream>>>(wacc, bv, x, g1, b1, Wd, hacc);
    // K6: ln1 recompute + ReLU + LN2 + classifier
    k6_final<<<8, 256, 0, stream>>>(wacc, bv, x, g1, b1, hacc, bd, g2, b2, Wc, bc, out);
}